// Round 6
// baseline (1198.117 us; speedup 1.0000x reference)
//
#include <hip/hip_runtime.h>
#include <hip/hip_cooperative_groups.h>
#include <math.h>

namespace cg = cooperative_groups;

#define NB 16
#define SL 32
#define H5 5120
#define K3 3072

typedef __attribute__((ext_vector_type(8))) short short8;
typedef __attribute__((ext_vector_type(4))) float floatx4;

__device__ __forceinline__ float sigf(float x) { return 1.0f / (1.0f + expf(-x)); }

__device__ __forceinline__ unsigned short f2bf(float x) {
  union { float f; unsigned int u; } v;
  v.f = x;
  unsigned int r = v.u + 0x7FFFu + ((v.u >> 16) & 1u);
  return (unsigned short)(r >> 16);
}

// meta layout (ints):
//  own 0, lt 512, li 1024, rt 1536, ri 2048, dep 2560, nn 3072(16),
//  dcnt 3088(32), lcnt 3120(32), dlist 3152(32*512), llist 19536(32*512)

// ---------------- zero ----------------
__global__ void k_zero(float* __restrict__ p, int n) {
  int i = blockIdx.x * blockDim.x + threadIdx.x;
  if (i < n) p[i] = 0.0f;
}

// ---------------- batch f32 -> bf16 conversion (6 segments) ----------------
__global__ void k_conv6(const float* s0, unsigned short* d0, int n0,
                        const float* s1, unsigned short* d1, int n1,
                        const float* s2, unsigned short* d2, int n2,
                        const float* s3, unsigned short* d3, int n3,
                        const float* s4, unsigned short* d4, int n4,
                        const float* s5, unsigned short* d5, int n5)
{
  const float* s; unsigned short* d; int n;
  switch (blockIdx.y) {
    case 0: s = s0; d = d0; n = n0; break;
    case 1: s = s1; d = d1; n = n1; break;
    case 2: s = s2; d = d2; n = n2; break;
    case 3: s = s3; d = d3; n = n3; break;
    case 4: s = s4; d = d4; n = n4; break;
    default: s = s5; d = d5; n = n5; break;
  }
  const int nf4 = n >> 2;
  for (int i = blockIdx.x * blockDim.x + threadIdx.x; i < nf4; i += gridDim.x * blockDim.x) {
    const float4 v = *(const float4*)&s[i * 4];
    ushort4 o;
    o.x = f2bf(v.x); o.y = f2bf(v.y); o.z = f2bf(v.z); o.w = f2bf(v.w);
    *(ushort4*)&d[i * 4] = o;
  }
}

// ---- generic f32 GEMM (only used for E1): out[r,g] = sum_k A[r,k]*W[g,k]
__global__ __launch_bounds__(256)
void k_gemm(const float* __restrict__ A, int lda,
            const float* __restrict__ W, int ldw,
            float* __restrict__ out, int N, int K)
{
  __shared__ __align__(16) float sm[2 * 16 * 68];
  float* As = sm;
  float* Ws = sm + 16 * 68;
  const int tid = threadIdx.x;
  const int tx = tid & 15, ty = tid >> 4;
  const int g0 = blockIdx.x * 64, r0 = blockIdx.y * 64;
  float acc[4][4];
#pragma unroll
  for (int i = 0; i < 4; ++i)
#pragma unroll
    for (int j = 0; j < 4; ++j) acc[i][j] = 0.0f;
  const int ks = tid & 15, rr = tid >> 4;
  for (int kt = 0; kt < K; kt += 16) {
#pragma unroll
    for (int rep = 0; rep < 4; ++rep) {
      As[ks * 68 + rep * 16 + rr] = A[(size_t)(r0 + rep * 16 + rr) * lda + kt + ks];
      Ws[ks * 68 + rep * 16 + rr] = W[(size_t)(g0 + rep * 16 + rr) * ldw + kt + ks];
    }
    __syncthreads();
#pragma unroll
    for (int k = 0; k < 16; ++k) {
      const float4 a4 = *(const float4*)&As[k * 68 + ty * 4];
      const float4 w4 = *(const float4*)&Ws[k * 68 + tx * 4];
      const float av[4] = {a4.x, a4.y, a4.z, a4.w};
      const float wv[4] = {w4.x, w4.y, w4.z, w4.w};
#pragma unroll
      for (int i = 0; i < 4; ++i)
#pragma unroll
        for (int j = 0; j < 4; ++j) acc[i][j] += av[i] * wv[j];
    }
    __syncthreads();
  }
#pragma unroll
  for (int i = 0; i < 4; ++i) {
    const int r = r0 + ty * 4 + i;
    float4 o;
    o.x = acc[i][0]; o.y = acc[i][1]; o.z = acc[i][2]; o.w = acc[i][3];
    *(float4*)&out[(size_t)r * N + g0 + tx * 4] = o;
  }
}

// ---------------- input projection MFMA: X = embB @ WihB^T ----------------
__global__ __launch_bounds__(256)
void k_xproj(const unsigned short* __restrict__ embB,
             const unsigned short* __restrict__ WfB, const unsigned short* __restrict__ WbB,
             float* __restrict__ Xf, float* __restrict__ Xb)
{
  const unsigned short* B = blockIdx.z ? WbB : WfB;
  float* out = blockIdx.z ? Xb : Xf;
  __shared__ __align__(16) unsigned short As[128 * 40];
  __shared__ __align__(16) unsigned short Bs[128 * 40];
  const int tid = threadIdx.x;
  const int g0 = blockIdx.x * 128;
  const int r0 = blockIdx.y * 128;
  const int wave = tid >> 6, lane = tid & 63;
  const int wm = wave >> 1, wn = wave & 1;
  const int l15 = lane & 15, quad = lane >> 4;
  floatx4 acc[4][4];
#pragma unroll
  for (int mt = 0; mt < 4; ++mt)
#pragma unroll
    for (int nt = 0; nt < 4; ++nt) acc[mt][nt] = (floatx4){0.f, 0.f, 0.f, 0.f};
  for (int kt = 0; kt < 512; kt += 32) {
    __syncthreads();
#pragma unroll
    for (int p = 0; p < 2; ++p) {
      const int i = tid + p * 256;
      const int row = i >> 2, q = i & 3;
      *(uint4*)&As[row * 40 + q * 8] = *(const uint4*)&embB[(size_t)(r0 + row) * 512 + kt + q * 8];
      *(uint4*)&Bs[row * 40 + q * 8] = *(const uint4*)&B[(size_t)(g0 + row) * 512 + kt + q * 8];
    }
    __syncthreads();
    short8 af[4], bfr[4];
#pragma unroll
    for (int mt = 0; mt < 4; ++mt)
      af[mt] = *(const short8*)&As[(wm * 64 + mt * 16 + l15) * 40 + quad * 8];
#pragma unroll
    for (int nt = 0; nt < 4; ++nt)
      bfr[nt] = *(const short8*)&Bs[(wn * 64 + nt * 16 + l15) * 40 + quad * 8];
#pragma unroll
    for (int mt = 0; mt < 4; ++mt)
#pragma unroll
      for (int nt = 0; nt < 4; ++nt)
        acc[mt][nt] = __builtin_amdgcn_mfma_f32_16x16x32_bf16(af[mt], bfr[nt], acc[mt][nt], 0, 0, 0);
  }
#pragma unroll
  for (int nt = 0; nt < 4; ++nt) {
    const int col = g0 + wn * 64 + nt * 16 + l15;
#pragma unroll
    for (int mt = 0; mt < 4; ++mt)
#pragma unroll
      for (int i = 0; i < 4; ++i) {
        const int row = r0 + wm * 64 + mt * 16 + quad * 4 + i;
        out[(size_t)row * 2048 + col] = acc[mt][nt][i];
      }
  }
}

// ---------------- big compose GEMM: gB[r,g] = bc[g] + U @ WcB^T ----------------
__global__ __launch_bounds__(256)
void k_mfma_gemm(const unsigned short* __restrict__ U, const unsigned short* __restrict__ WcB,
                 const float* __restrict__ bc, float* __restrict__ gB)
{
  __shared__ __align__(16) unsigned short As[128 * 40];
  __shared__ __align__(16) unsigned short Bs[64 * 40];
  const int bid = blockIdx.x;
  const int r0 = (bid / 80) * 128;
  const int g0 = (bid % 80) * 64;
  const int tid = threadIdx.x;
  const int wave = tid >> 6, lane = tid & 63;
  const int wm = wave >> 1, wn = wave & 1;
  const int l15 = lane & 15, quad = lane >> 4;
  floatx4 acc[4][2];
#pragma unroll
  for (int mf = 0; mf < 4; ++mf)
#pragma unroll
    for (int nt = 0; nt < 2; ++nt) acc[mf][nt] = (floatx4){0.f, 0.f, 0.f, 0.f};
  const int a_row = tid >> 2, a_q = tid & 3;
  for (int kt = 0; kt < K3; kt += 32) {
    __syncthreads();
#pragma unroll
    for (int p = 0; p < 2; ++p) {
      const int i = tid + p * 256;
      const int row = i >> 2, q = i & 3;
      *(uint4*)&As[row * 40 + q * 8] = *(const uint4*)&U[(size_t)(r0 + row) * K3 + kt + q * 8];
    }
    *(uint4*)&Bs[a_row * 40 + a_q * 8] = *(const uint4*)&WcB[(size_t)(g0 + a_row) * K3 + kt + a_q * 8];
    __syncthreads();
    short8 af[4], bfr[2];
#pragma unroll
    for (int mf = 0; mf < 4; ++mf)
      af[mf] = *(const short8*)&As[(wm * 64 + mf * 16 + l15) * 40 + quad * 8];
#pragma unroll
    for (int nt = 0; nt < 2; ++nt)
      bfr[nt] = *(const short8*)&Bs[(wn * 32 + nt * 16 + l15) * 40 + quad * 8];
#pragma unroll
    for (int mf = 0; mf < 4; ++mf)
#pragma unroll
      for (int nt = 0; nt < 2; ++nt)
        acc[mf][nt] = __builtin_amdgcn_mfma_f32_16x16x32_bf16(af[mf], bfr[nt], acc[mf][nt], 0, 0, 0);
  }
#pragma unroll
  for (int nt = 0; nt < 2; ++nt) {
    const int col = g0 + wn * 32 + nt * 16 + l15;
    const float bias = bc[col];
#pragma unroll
    for (int mf = 0; mf < 4; ++mf)
#pragma unroll
      for (int i = 0; i < 4; ++i) {
        const int row = r0 + wm * 64 + mf * 16 + quad * 4 + i;
        gB[(size_t)row * H5 + col] = acc[mf][nt][i] + bias;
      }
  }
}

// ---------------- one LSTM timestep, MFMA version ----------------
__global__ __launch_bounds__(256)
void k_stepm(const float* __restrict__ Xf, const float* __restrict__ Xb,
             const unsigned short* __restrict__ WhfB, const unsigned short* __restrict__ WhbB,
             const float* __restrict__ bf, const float* __restrict__ bb,
             const int* __restrict__ len,
             unsigned short* __restrict__ hbB, float* __restrict__ cbuf,
             float* __restrict__ hs, float* __restrict__ cs, int t)
{
  const int dir = blockIdx.y;
  const int hjt = blockIdx.x;
  const int tid = threadIdx.x;
  const int wave = tid >> 6, lane = tid & 63;
  const int l15 = lane & 15, quad = lane >> 4;
  const unsigned short* Wh = dir ? WhbB : WhfB;
  const float* bias = dir ? bb : bf;
  const float* X = dir ? Xb : Xf;
  const int pp = t & 1;
  const unsigned short* hp = hbB + (size_t)(dir * 2 + pp) * 8192;
  unsigned short* hn = hbB + (size_t)(dir * 2 + (pp ^ 1)) * 8192;
  const float* cp = cbuf + (size_t)(dir * 2 + pp) * 8192;
  float* cn = cbuf + (size_t)(dir * 2 + (pp ^ 1)) * 8192;

  __shared__ float sg[4 * 16 * 17];
  floatx4 acc = (floatx4){0.f, 0.f, 0.f, 0.f};
  const int jg = wave * 512 + hjt * 16 + l15;
  for (int kt = 0; kt < 512; kt += 32) {
    const short8 a = *(const short8*)&hp[(size_t)l15 * 512 + kt + quad * 8];
    const short8 b = *(const short8*)&Wh[(size_t)jg * 512 + kt + quad * 8];
    acc = __builtin_amdgcn_mfma_f32_16x16x32_bf16(a, b, acc, 0, 0, 0);
  }
#pragma unroll
  for (int i = 0; i < 4; ++i)
    sg[wave * 272 + (quad * 4 + i) * 17 + l15] = acc[i];
  __syncthreads();
  const int b = tid >> 4, j = tid & 15;
  const int hj = hjt * 16 + j;
  const int Lb = len[b];
  int xidx = t;
  if (dir) xidx = (t < Lb) ? (Lb - 1 - t) : t;
  const float* xr = X + (size_t)(b * SL + xidx) * 2048;
  const float gi = sg[0 * 272 + b * 17 + j] + xr[hj] + bias[hj];
  const float gf = sg[1 * 272 + b * 17 + j] + xr[512 + hj] + bias[512 + hj];
  const float gg = sg[2 * 272 + b * 17 + j] + xr[1024 + hj] + bias[1024 + hj];
  const float go = sg[3 * 272 + b * 17 + j] + xr[1536 + hj] + bias[1536 + hj];
  const float cprev = cp[b * 512 + hj];
  const float cnew = sigf(gf) * cprev + sigf(gi) * tanhf(gg);
  const float hnew = sigf(go) * tanhf(cnew);
  cn[b * 512 + hj] = cnew;
  hn[b * 512 + hj] = f2bf(hnew);
  const int pos = dir ? xidx : t;
  const int col = dir ? (512 + hj) : hj;
  hs[(size_t)(b * SL + pos) * 1024 + col] = hnew;
  cs[(size_t)(b * SL + pos) * 1024 + col] = cnew;
}

// ---------------- precompute ALL segment argmax splits ----------------
__global__ __launch_bounds__(256)
void k_score(const float* __restrict__ E1, const float* __restrict__ Wr1,
             const float* __restrict__ Wr2, const int* __restrict__ len,
             int* __restrict__ ksplit)
{
  const int b = blockIdx.x;
  const int s = blockIdx.y;
  const int L = len[b];
  if (s + 2 > L) return;
  const int tid = threadIdx.x;
  __shared__ float e[32 * 257];
  __shared__ float w1p[256];
  __shared__ float w2s[256];
  __shared__ float red[32 * 8];
  __shared__ float sc[32];
  const int nrow = 32 - s;
  for (int i = tid; i < nrow * 256; i += 256) {
    const int rr = i >> 8, q = i & 255;
    e[rr * 257 + q] = E1[(size_t)(b * SL + s + rr) * 256 + q];
  }
  w1p[tid] = Wr1[tid * 513 + 512];
  w2s[tid] = Wr2[tid];
  __syncthreads();
  const int t_ = tid & 31, jg = tid >> 5;
  const int lmax = L - s;
  for (int l = 2; l <= lmax; ++l) {
    float part = 0.0f;
    if (t_ < l) {
      const float pos = 2.0f * (float)t_ / (float)l - 1.0f;
      const float* er = e + t_ * 257;
      for (int q = jg * 32; q < jg * 32 + 32; ++q) {
        const float v = er[q] + pos * w1p[q];
        part += fmaxf(v, 0.0f) * w2s[q];
      }
    }
    red[t_ * 8 + jg] = part;
    __syncthreads();
    if (jg == 0 && t_ < l) {
      float su = 0.0f;
      for (int q = 0; q < 8; ++q) su += red[t_ * 8 + q];
      sc[t_] = su;
    }
    __syncthreads();
    if (tid == 0) {
      int k = 0;
      float best = sc[0];
      for (int q = 1; q < l; ++q)
        if (sc[q] > best) { best = sc[q]; k = q; }
      ksplit[(b * 32 + s) * 33 + l] = k;
    }
    __syncthreads();
  }
}

// ---------------- DFS walk using precomputed splits ----------------
__global__ __launch_bounds__(64)
void k_walk(const int* __restrict__ ksplit, const int* __restrict__ len,
            int* __restrict__ meta)
{
  const int b = blockIdx.x;
  const int tid = threadIdx.x;
  __shared__ int ks[32 * 33];
  __shared__ int stk[96];
  for (int i = tid; i < 32 * 33; i += 64) ks[i] = ksplit[b * 1056 + i];
  __syncthreads();
  if (tid != 0) return;
  int* own = meta;
  int* lt = meta + 512;
  int* li = meta + 1024;
  int* rt = meta + 1536;
  int* ri = meta + 2048;
  int* dep = meta + 2560;
  int* nn = meta + 3072;
  int* dcnt = meta + 3088;
  int* lcnt = meta + 3120;
  int* dlist = meta + 3152;
  int* llist = meta + 19536;
  int sp = 0, nn_ = 1;
  stk[0] = 0; stk[1] = len[b]; stk[2] = 0;
  sp = 1;
  while (sp > 0) {
    sp--;
    const int s = stk[sp * 3], eN = stk[sp * 3 + 1], nid = stk[sp * 3 + 2];
    const int l = eN - s;
    const int k = ks[s * 33 + l];
    const int m = b * 32 + nid;
    own[m] = s + k;
    if (k == 0) { lt[m] = 0; li[m] = 0; }
    else if (k == 1) { lt[m] = 1; li[m] = s; }
    else {
      const int id = nn_++;
      lt[m] = 2; li[m] = id;
      stk[sp * 3] = s; stk[sp * 3 + 1] = s + k; stk[sp * 3 + 2] = id; sp++;
    }
    const int rl = l - k - 1;
    if (rl == 0) { rt[m] = 0; ri[m] = 0; }
    else if (rl == 1) { rt[m] = 1; ri[m] = s + k + 1; }
    else {
      const int id = nn_++;
      rt[m] = 2; ri[m] = id;
      stk[sp * 3] = s + k + 1; stk[sp * 3 + 1] = eN; stk[sp * 3 + 2] = id; sp++;
    }
  }
  nn[b] = nn_;
  for (int i = nn_ - 1; i >= 0; --i) {
    const int m = b * 32 + i;
    int d = 1;
    if (lt[m] == 2) d = max(d, dep[b * 32 + li[m]] + 1);
    if (rt[m] == 2) d = max(d, dep[b * 32 + ri[m]] + 1);
    dep[m] = d;
  }
  for (int i = 0; i < nn_; ++i) {
    const int m = b * 32 + i;
    const int r = dep[m];
    const int idx = atomicAdd(&dcnt[r], 1);
    dlist[r * 512 + idx] = m;
    if (lt[m] == 2 || rt[m] == 2) {
      const int lx = atomicAdd(&lcnt[r], 1);
      llist[r * 512 + lx] = m;
    }
  }
}

// ---------------- build U (bf16) = [hl_leaf|0 , hr_leaf|0 , hx] per node ----------------
__global__ __launch_bounds__(256)
void k_ubuild(const float* __restrict__ hs, const int* __restrict__ meta,
              unsigned short* __restrict__ U)
{
  const int id = blockIdx.x, b = blockIdx.y;
  const int tid = threadIdx.x;
  const int* own = meta;
  const int* lt = meta + 512;
  const int* li = meta + 1024;
  const int* rt = meta + 1536;
  const int* ri = meta + 2048;
  const int* nn = meta + 3072;
  const int m = b * 32 + id;
  unsigned short* u = U + (size_t)m * K3;
  if (id >= nn[b]) {
    for (int i = tid; i < K3; i += 256) u[i] = 0;
    return;
  }
  const float* hl = (lt[m] == 1) ? hs + (size_t)(b * 32 + li[m]) * 1024 : nullptr;
  const float* hr = (rt[m] == 1) ? hs + (size_t)(b * 32 + ri[m]) * 1024 : nullptr;
  const float* hx = hs + (size_t)(b * 32 + own[m]) * 1024;
  for (int i = tid; i < 1024; i += 256) {
    u[i] = hl ? f2bf(hl[i]) : 0;
    u[1024 + i] = hr ? f2bf(hr[i]) : 0;
    u[2048 + i] = f2bf(hx[i]);
  }
}

// ---------------- fused gate helper (one column) ----------------
__device__ __forceinline__ void do_gate(int node, int hj, const float* lk,
                                        const int* lt, const int* li,
                                        const int* rt, const int* ri,
                                        const float* gB, const float* cs,
                                        float* nodeh, float* nodec,
                                        unsigned short* nodehb, float* out)
{
  const int base = node & ~31;
  const int ltv = lt[node], rtv = rt[node];
  float cl = 0.f, cr = 0.f;
  if (ltv == 2) cl = nodec[(size_t)(base + li[node]) * 1024 + hj];
  else if (ltv == 1) cl = cs[(size_t)(base + li[node]) * 1024 + hj];
  if (rtv == 2) cr = nodec[(size_t)(base + ri[node]) * 1024 + hj];
  else if (rtv == 1) cr = cs[(size_t)(base + ri[node]) * 1024 + hj];
  const float* g = &gB[(size_t)node * H5 + hj];
  const float gi  = g[0]    + lk[0];
  const float gfl = g[1024] + lk[1];
  const float gfr = g[2048] + lk[2];
  const float gu  = g[3072] + lk[3];
  const float go  = g[4096] + lk[4];
  const float c = sigf(gfl) * cl + sigf(gfr) * cr + sigf(gi) * tanhf(gu);
  const float h = sigf(go) * tanhf(c);
  nodeh[(size_t)node * 1024 + hj] = h;
  nodec[(size_t)node * 1024 + hj] = c;
  nodehb[(size_t)node * 1024 + hj] = f2bf(h);
  if ((node & 31) == 0) {
    const int b = node >> 5;
    out[b * 1024 + hj] = h;
    out[16384 + b * 1024 + hj] = c;
  }
}

// ---------------- persistent cooperative rounds kernel ----------------
// grid 256 (1 block/CU), block 256. Block bid owns h-columns [bid*4, bid*4+4)
// i.e. the 20 Wc rows {g*1024 + bid*4 + c}. Rounds loop with grid.sync();
// each CU re-reads the same 80 KB weight slice every round -> L2-resident.
// Link GEMM: 16-node m-chunks, MFMA 16x16x32, K split across 4 waves
// (16 super-steps of 32 k each), cross-wave reduce in LDS, fused gating.
__global__ __launch_bounds__(256)
void k_rounds(const unsigned short* __restrict__ WcB, const int* __restrict__ meta,
              const float* __restrict__ gB, const float* __restrict__ cs,
              float* __restrict__ nodeh, float* __restrict__ nodec,
              unsigned short* __restrict__ nodehb, float* __restrict__ out)
{
  cg::grid_group grid = cg::this_grid();
  const int* lt = meta + 512;
  const int* li = meta + 1024;
  const int* rt = meta + 1536;
  const int* ri = meta + 2048;
  const int* dcnt = meta + 3088;
  const int* dlist = meta + 3152;
  const int* llist = meta + 19536;
  const int bid = blockIdx.x;
  const int hj0 = bid * 4;
  const int tid = threadIdx.x;
  const int wave = tid >> 6, lane = tid & 63;
  const int l15 = lane & 15, quad = lane >> 4;

  __shared__ __align__(16) unsigned short As[16 * 136];
  __shared__ __align__(16) unsigned short Bs[20 * 136];
  __shared__ float sg4[4 * 16 * 20];
  __shared__ int snode[16];
  __shared__ int sofs[2][16];
  const uint4 z4 = make_uint4(0, 0, 0, 0);

  // ---- round 1: gate-only (all children are leaves) ----
  {
    const int cnt = dcnt[1];
    const int c = tid & 3;
    const float lk[5] = {0.f, 0.f, 0.f, 0.f, 0.f};
    for (int m = tid >> 2; m < cnt; m += 64) {
      const int node = dlist[512 + m];
      do_gate(node, hj0 + c, lk, lt, li, rt, ri, gB, cs, nodeh, nodec, nodehb, out);
    }
  }

  // ---- rounds >= 2: link MFMA + fused gate ----
  for (int r = 2; r <= 31; ++r) {
    if (dcnt[r] == 0) break;   // depths are contiguous
    __threadfence();
    grid.sync();
    const int cnt = dcnt[r];   // == lcnt[r] for r>=2 (every node has an internal child)
    for (int m0 = 0; m0 < cnt; m0 += 16) {
      __syncthreads();
      if (tid < 16) {
        int node = -1, ol = -1, orr = -1;
        if (m0 + tid < cnt) {
          node = llist[r * 512 + m0 + tid];
          const int base = node & ~31;
          if (lt[node] == 2) ol = (base + li[node]) * 1024;
          if (rt[node] == 2) orr = (base + ri[node]) * 1024;
        }
        snode[tid] = node;
        sofs[0][tid] = ol;
        sofs[1][tid] = orr;
      }
      __syncthreads();
      floatx4 acc0 = (floatx4){0.f, 0.f, 0.f, 0.f};
      floatx4 acc1 = (floatx4){0.f, 0.f, 0.f, 0.f};
      for (int s = 0; s < 16; ++s) {
        __syncthreads();
        {  // stage A: 16 nodes x 128 k (4 wave-windows of 32)
          const int row = tid >> 4, colq = tid & 15;
          const int kglob = (colq >> 2) * 512 + s * 32 + (colq & 3) * 8;
          const int side = kglob >> 10, kl = kglob & 1023;
          const int ofs = sofs[side][row];
          *(uint4*)&As[row * 136 + colq * 8] =
              (ofs >= 0) ? *(const uint4*)&nodehb[(size_t)ofs + kl] : z4;
        }
        for (int slot = tid; slot < 320; slot += 256) {  // stage B: 20 rows x 128 k
          const int row = slot >> 4, colq = slot & 15;
          const int grow = (row >> 2) * 1024 + hj0 + (row & 3);
          const int kglob = (colq >> 2) * 512 + s * 32 + (colq & 3) * 8;
          *(uint4*)&Bs[row * 136 + colq * 8] =
              *(const uint4*)&WcB[(size_t)grow * K3 + kglob];
        }
        __syncthreads();
        const short8 a = *(const short8*)&As[l15 * 136 + wave * 32 + quad * 8];
        const short8 b0 = *(const short8*)&Bs[l15 * 136 + wave * 32 + quad * 8];
        const short8 b1 = *(const short8*)&Bs[(4 + l15) * 136 + wave * 32 + quad * 8];
        acc0 = __builtin_amdgcn_mfma_f32_16x16x32_bf16(a, b0, acc0, 0, 0, 0);
        acc1 = __builtin_amdgcn_mfma_f32_16x16x32_bf16(a, b1, acc1, 0, 0, 0);
      }
      __syncthreads();
      // cross-wave partial sums: D row(node)=quad*4+i, col(weight row)=l15 / 4+l15
#pragma unroll
      for (int i = 0; i < 4; ++i) {
        sg4[(wave * 16 + quad * 4 + i) * 20 + l15] = acc0[i];
        if (l15 >= 12) sg4[(wave * 16 + quad * 4 + i) * 20 + 4 + l15] = acc1[i];
      }
      __syncthreads();
      if (tid < 64) {
        const int m = tid >> 2, c = tid & 3;
        if (m0 + m < cnt) {
          float lk[5];
#pragma unroll
          for (int g = 0; g < 5; ++g) {
            const int rw = g * 4 + c;
            lk[g] = sg4[(0 * 16 + m) * 20 + rw] + sg4[(1 * 16 + m) * 20 + rw] +
                    sg4[(2 * 16 + m) * 20 + rw] + sg4[(3 * 16 + m) * 20 + rw];
          }
          do_gate(snode[m], hj0 + c, lk, lt, li, rt, ri, gB, cs,
                  nodeh, nodec, nodehb, out);
        }
      }
    }
  }
}

extern "C" void kernel_launch(void* const* d_in, const int* in_sizes, int n_in,
                              void* d_out, int out_size, void* d_ws, size_t ws_size,
                              hipStream_t stream) {
  const float* emb = (const float*)d_in[0];
  const int* len = (const int*)d_in[1];
  const float* Wihf = (const float*)d_in[2];
  const float* Whhf = (const float*)d_in[3];
  const float* bf = (const float*)d_in[4];
  const float* Wihb = (const float*)d_in[5];
  const float* Whhb = (const float*)d_in[6];
  const float* bb = (const float*)d_in[7];
  const float* Wr1 = (const float*)d_in[8];
  const float* Wr2 = (const float*)d_in[9];
  const float* Wc = (const float*)d_in[10];
  const float* bc = (const float*)d_in[11];
  float* out = (float*)d_out;

  float* ws = (float*)d_ws;
  float* Xf = ws;                                         // 1048576 f
  float* Xb = Xf + 1048576;                               // 1048576 f
  float* hs = Xb + 1048576;                               // 524288 f
  float* cs = hs + 524288;                                // 524288 f
  float* E1 = cs + 524288;                                // 131072 f
  unsigned short* U = (unsigned short*)(E1 + 131072);     // 786432 f
  float* gB = (float*)U + 786432;                         // 2621440 f
  float* nodeh = gB + 2621440;                            // 524288 f
  float* nodec = nodeh + 524288;                          // 524288 f
  unsigned short* nodehb = (unsigned short*)(nodec + 524288);     // 262144 f
  float* cbuf = (float*)nodehb + 262144;                  // 32768 f
  unsigned short* hbB = (unsigned short*)(cbuf + 32768);  // 16384 f
  unsigned short* WcB = (unsigned short*)((float*)hbB + 16384);   // 7864320 f
  unsigned short* WihfB = WcB + 15728640;                 // 1048576 sh
  unsigned short* WihbB = WihfB + 1048576;
  unsigned short* WhhfB = WihbB + 1048576;
  unsigned short* WhhbB = WhhfB + 1048576;
  unsigned short* embB = WhhbB + 1048576;                 // 262144 sh
  int* meta = (int*)(embB + 262144);                      // ~36K ints
  int* ksplit = meta + 36096;                             // 16*1056 ints

  // zero c/h ping-pong state and per-depth counters
  k_zero<<<192, 256, 0, stream>>>(cbuf, 49152);
  k_zero<<<1, 64, 0, stream>>>((float*)(meta + 3088), 64);
  // bf16 conversions
  k_conv6<<<dim3(1920, 6), 256, 0, stream>>>(
      Wc, WcB, 15728640, Wihf, WihfB, 1048576, Wihb, WihbB, 1048576,
      Whhf, WhhfB, 1048576, Whhb, WhhbB, 1048576, emb, embB, 262144);
  // rank projection (f32)
  k_gemm<<<dim3(4, 8), 256, 0, stream>>>(emb, 512, Wr1, 513, E1, 256, 512);
  // input projections
  k_xproj<<<dim3(16, 4, 2), 256, 0, stream>>>(embB, WihfB, WihbB, Xf, Xb);
  // recurrent scan
  for (int t = 0; t < SL; ++t)
    k_stepm<<<dim3(32, 2), 256, 0, stream>>>(Xf, Xb, WhhfB, WhhbB, bf, bb, len,
                                             hbB, cbuf, hs, cs, t);
  // split table (parallel) + DFS walk (cheap)
  k_score<<<dim3(16, 31), 256, 0, stream>>>(E1, Wr1, Wr2, len, ksplit);
  k_walk<<<16, 64, 0, stream>>>(ksplit, len, meta);
  // precomputable part of every compose
  k_ubuild<<<dim3(32, 16), 256, 0, stream>>>(hs, meta, U);
  k_mfma_gemm<<<320, 256, 0, stream>>>(U, WcB, bc, gB);
  // ALL compose rounds + gating + output in ONE cooperative persistent kernel
  {
    void* args[] = {(void*)&WcB, (void*)&meta, (void*)&gB, (void*)&cs,
                    (void*)&nodeh, (void*)&nodec, (void*)&nodehb, (void*)&out};
    hipLaunchCooperativeKernel((const void*)k_rounds, dim3(256), dim3(256),
                               args, 0, stream);
  }
}

// Round 7
// 759.020 us; speedup vs baseline: 1.5785x; 1.5785x over previous
//
#include <hip/hip_runtime.h>
#include <math.h>

#define NB 16
#define SL 32
#define H5 5120
#define K3 3072
#define MAXC 8

typedef __attribute__((ext_vector_type(8))) short short8;
typedef __attribute__((ext_vector_type(4))) float floatx4;

__device__ __forceinline__ float sigf(float x) { return 1.0f / (1.0f + expf(-x)); }

__device__ __forceinline__ unsigned short f2bf(float x) {
  union { float f; unsigned int u; } v;
  v.f = x;
  unsigned int r = v.u + 0x7FFFu + ((v.u >> 16) & 1u);
  return (unsigned short)(r >> 16);
}

// meta layout (ints):
//  own 0, lt 512, li 1024, rt 1536, ri 2048, dep 2560, nn 3072(16),
//  dcnt 3088(32), lcnt 3120(32), dlist 3152(32*512), llist 19536(32*512)

// ---------------- zero ----------------
__global__ void k_zero(float* __restrict__ p, int n) {
  int i = blockIdx.x * blockDim.x + threadIdx.x;
  if (i < n) p[i] = 0.0f;
}

// ---------------- batch f32 -> bf16 conversion (6 segments) ----------------
__global__ void k_conv6(const float* s0, unsigned short* d0, int n0,
                        const float* s1, unsigned short* d1, int n1,
                        const float* s2, unsigned short* d2, int n2,
                        const float* s3, unsigned short* d3, int n3,
                        const float* s4, unsigned short* d4, int n4,
                        const float* s5, unsigned short* d5, int n5)
{
  const float* s; unsigned short* d; int n;
  switch (blockIdx.y) {
    case 0: s = s0; d = d0; n = n0; break;
    case 1: s = s1; d = d1; n = n1; break;
    case 2: s = s2; d = d2; n = n2; break;
    case 3: s = s3; d = d3; n = n3; break;
    case 4: s = s4; d = d4; n = n4; break;
    default: s = s5; d = d5; n = n5; break;
  }
  const int nf4 = n >> 2;
  for (int i = blockIdx.x * blockDim.x + threadIdx.x; i < nf4; i += gridDim.x * blockDim.x) {
    const float4 v = *(const float4*)&s[i * 4];
    ushort4 o;
    o.x = f2bf(v.x); o.y = f2bf(v.y); o.z = f2bf(v.z); o.w = f2bf(v.w);
    *(ushort4*)&d[i * 4] = o;
  }
}

// ---- generic f32 GEMM (only used for E1): out[r,g] = sum_k A[r,k]*W[g,k]
__global__ __launch_bounds__(256)
void k_gemm(const float* __restrict__ A, int lda,
            const float* __restrict__ W, int ldw,
            float* __restrict__ out, int N, int K)
{
  __shared__ __align__(16) float sm[2 * 16 * 68];
  float* As = sm;
  float* Ws = sm + 16 * 68;
  const int tid = threadIdx.x;
  const int tx = tid & 15, ty = tid >> 4;
  const int g0 = blockIdx.x * 64, r0 = blockIdx.y * 64;
  float acc[4][4];
#pragma unroll
  for (int i = 0; i < 4; ++i)
#pragma unroll
    for (int j = 0; j < 4; ++j) acc[i][j] = 0.0f;
  const int ks = tid & 15, rr = tid >> 4;
  for (int kt = 0; kt < K; kt += 16) {
#pragma unroll
    for (int rep = 0; rep < 4; ++rep) {
      As[ks * 68 + rep * 16 + rr] = A[(size_t)(r0 + rep * 16 + rr) * lda + kt + ks];
      Ws[ks * 68 + rep * 16 + rr] = W[(size_t)(g0 + rep * 16 + rr) * ldw + kt + ks];
    }
    __syncthreads();
#pragma unroll
    for (int k = 0; k < 16; ++k) {
      const float4 a4 = *(const float4*)&As[k * 68 + ty * 4];
      const float4 w4 = *(const float4*)&Ws[k * 68 + tx * 4];
      const float av[4] = {a4.x, a4.y, a4.z, a4.w};
      const float wv[4] = {w4.x, w4.y, w4.z, w4.w};
#pragma unroll
      for (int i = 0; i < 4; ++i)
#pragma unroll
        for (int j = 0; j < 4; ++j) acc[i][j] += av[i] * wv[j];
    }
    __syncthreads();
  }
#pragma unroll
  for (int i = 0; i < 4; ++i) {
    const int r = r0 + ty * 4 + i;
    float4 o;
    o.x = acc[i][0]; o.y = acc[i][1]; o.z = acc[i][2]; o.w = acc[i][3];
    *(float4*)&out[(size_t)r * N + g0 + tx * 4] = o;
  }
}

// ---------------- input projection MFMA: X = embB @ WihB^T ----------------
__global__ __launch_bounds__(256)
void k_xproj(const unsigned short* __restrict__ embB,
             const unsigned short* __restrict__ WfB, const unsigned short* __restrict__ WbB,
             float* __restrict__ Xf, float* __restrict__ Xb)
{
  const unsigned short* B = blockIdx.z ? WbB : WfB;
  float* out = blockIdx.z ? Xb : Xf;
  __shared__ __align__(16) unsigned short As[128 * 40];
  __shared__ __align__(16) unsigned short Bs[128 * 40];
  const int tid = threadIdx.x;
  const int g0 = blockIdx.x * 128;
  const int r0 = blockIdx.y * 128;
  const int wave = tid >> 6, lane = tid & 63;
  const int wm = wave >> 1, wn = wave & 1;
  const int l15 = lane & 15, quad = lane >> 4;
  floatx4 acc[4][4];
#pragma unroll
  for (int mt = 0; mt < 4; ++mt)
#pragma unroll
    for (int nt = 0; nt < 4; ++nt) acc[mt][nt] = (floatx4){0.f, 0.f, 0.f, 0.f};
  for (int kt = 0; kt < 512; kt += 32) {
    __syncthreads();
#pragma unroll
    for (int p = 0; p < 2; ++p) {
      const int i = tid + p * 256;
      const int row = i >> 2, q = i & 3;
      *(uint4*)&As[row * 40 + q * 8] = *(const uint4*)&embB[(size_t)(r0 + row) * 512 + kt + q * 8];
      *(uint4*)&Bs[row * 40 + q * 8] = *(const uint4*)&B[(size_t)(g0 + row) * 512 + kt + q * 8];
    }
    __syncthreads();
    short8 af[4], bfr[4];
#pragma unroll
    for (int mt = 0; mt < 4; ++mt)
      af[mt] = *(const short8*)&As[(wm * 64 + mt * 16 + l15) * 40 + quad * 8];
#pragma unroll
    for (int nt = 0; nt < 4; ++nt)
      bfr[nt] = *(const short8*)&Bs[(wn * 64 + nt * 16 + l15) * 40 + quad * 8];
#pragma unroll
    for (int mt = 0; mt < 4; ++mt)
#pragma unroll
      for (int nt = 0; nt < 4; ++nt)
        acc[mt][nt] = __builtin_amdgcn_mfma_f32_16x16x32_bf16(af[mt], bfr[nt], acc[mt][nt], 0, 0, 0);
  }
#pragma unroll
  for (int nt = 0; nt < 4; ++nt) {
    const int col = g0 + wn * 64 + nt * 16 + l15;
#pragma unroll
    for (int mt = 0; mt < 4; ++mt)
#pragma unroll
      for (int i = 0; i < 4; ++i) {
        const int row = r0 + wm * 64 + mt * 16 + quad * 4 + i;
        out[(size_t)row * 2048 + col] = acc[mt][nt][i];
      }
  }
}

// ---------------- big compose GEMM: gB[r,g] = bc[g] + U @ WcB^T ----------------
__global__ __launch_bounds__(256)
void k_mfma_gemm(const unsigned short* __restrict__ U, const unsigned short* __restrict__ WcB,
                 const float* __restrict__ bc, float* __restrict__ gB)
{
  __shared__ __align__(16) unsigned short As[128 * 40];
  __shared__ __align__(16) unsigned short Bs[64 * 40];
  const int bid = blockIdx.x;
  const int r0 = (bid / 80) * 128;
  const int g0 = (bid % 80) * 64;
  const int tid = threadIdx.x;
  const int wave = tid >> 6, lane = tid & 63;
  const int wm = wave >> 1, wn = wave & 1;
  const int l15 = lane & 15, quad = lane >> 4;
  floatx4 acc[4][2];
#pragma unroll
  for (int mf = 0; mf < 4; ++mf)
#pragma unroll
    for (int nt = 0; nt < 2; ++nt) acc[mf][nt] = (floatx4){0.f, 0.f, 0.f, 0.f};
  const int a_row = tid >> 2, a_q = tid & 3;
  for (int kt = 0; kt < K3; kt += 32) {
    __syncthreads();
#pragma unroll
    for (int p = 0; p < 2; ++p) {
      const int i = tid + p * 256;
      const int row = i >> 2, q = i & 3;
      *(uint4*)&As[row * 40 + q * 8] = *(const uint4*)&U[(size_t)(r0 + row) * K3 + kt + q * 8];
    }
    *(uint4*)&Bs[a_row * 40 + a_q * 8] = *(const uint4*)&WcB[(size_t)(g0 + a_row) * K3 + kt + a_q * 8];
    __syncthreads();
    short8 af[4], bfr[2];
#pragma unroll
    for (int mf = 0; mf < 4; ++mf)
      af[mf] = *(const short8*)&As[(wm * 64 + mf * 16 + l15) * 40 + quad * 8];
#pragma unroll
    for (int nt = 0; nt < 2; ++nt)
      bfr[nt] = *(const short8*)&Bs[(wn * 32 + nt * 16 + l15) * 40 + quad * 8];
#pragma unroll
    for (int mf = 0; mf < 4; ++mf)
#pragma unroll
      for (int nt = 0; nt < 2; ++nt)
        acc[mf][nt] = __builtin_amdgcn_mfma_f32_16x16x32_bf16(af[mf], bfr[nt], acc[mf][nt], 0, 0, 0);
  }
#pragma unroll
  for (int nt = 0; nt < 2; ++nt) {
    const int col = g0 + wn * 32 + nt * 16 + l15;
    const float bias = bc[col];
#pragma unroll
    for (int mf = 0; mf < 4; ++mf)
#pragma unroll
      for (int i = 0; i < 4; ++i) {
        const int row = r0 + wm * 64 + mf * 16 + quad * 4 + i;
        gB[(size_t)row * H5 + col] = acc[mf][nt][i] + bias;
      }
  }
}

// ---------------- one LSTM timestep, MFMA version ----------------
__global__ __launch_bounds__(256)
void k_stepm(const float* __restrict__ Xf, const float* __restrict__ Xb,
             const unsigned short* __restrict__ WhfB, const unsigned short* __restrict__ WhbB,
             const float* __restrict__ bf, const float* __restrict__ bb,
             const int* __restrict__ len,
             unsigned short* __restrict__ hbB, float* __restrict__ cbuf,
             float* __restrict__ hs, float* __restrict__ cs, int t)
{
  const int dir = blockIdx.y;
  const int hjt = blockIdx.x;
  const int tid = threadIdx.x;
  const int wave = tid >> 6, lane = tid & 63;
  const int l15 = lane & 15, quad = lane >> 4;
  const unsigned short* Wh = dir ? WhbB : WhfB;
  const float* bias = dir ? bb : bf;
  const float* X = dir ? Xb : Xf;
  const int pp = t & 1;
  const unsigned short* hp = hbB + (size_t)(dir * 2 + pp) * 8192;
  unsigned short* hn = hbB + (size_t)(dir * 2 + (pp ^ 1)) * 8192;
  const float* cp = cbuf + (size_t)(dir * 2 + pp) * 8192;
  float* cn = cbuf + (size_t)(dir * 2 + (pp ^ 1)) * 8192;

  __shared__ float sg[4 * 16 * 17];
  floatx4 acc = (floatx4){0.f, 0.f, 0.f, 0.f};
  const int jg = wave * 512 + hjt * 16 + l15;
  for (int kt = 0; kt < 512; kt += 32) {
    const short8 a = *(const short8*)&hp[(size_t)l15 * 512 + kt + quad * 8];
    const short8 b = *(const short8*)&Wh[(size_t)jg * 512 + kt + quad * 8];
    acc = __builtin_amdgcn_mfma_f32_16x16x32_bf16(a, b, acc, 0, 0, 0);
  }
#pragma unroll
  for (int i = 0; i < 4; ++i)
    sg[wave * 272 + (quad * 4 + i) * 17 + l15] = acc[i];
  __syncthreads();
  const int b = tid >> 4, j = tid & 15;
  const int hj = hjt * 16 + j;
  const int Lb = len[b];
  int xidx = t;
  if (dir) xidx = (t < Lb) ? (Lb - 1 - t) : t;
  const float* xr = X + (size_t)(b * SL + xidx) * 2048;
  const float gi = sg[0 * 272 + b * 17 + j] + xr[hj] + bias[hj];
  const float gf = sg[1 * 272 + b * 17 + j] + xr[512 + hj] + bias[512 + hj];
  const float gg = sg[2 * 272 + b * 17 + j] + xr[1024 + hj] + bias[1024 + hj];
  const float go = sg[3 * 272 + b * 17 + j] + xr[1536 + hj] + bias[1536 + hj];
  const float cprev = cp[b * 512 + hj];
  const float cnew = sigf(gf) * cprev + sigf(gi) * tanhf(gg);
  const float hnew = sigf(go) * tanhf(cnew);
  cn[b * 512 + hj] = cnew;
  hn[b * 512 + hj] = f2bf(hnew);
  const int pos = dir ? xidx : t;
  const int col = dir ? (512 + hj) : hj;
  hs[(size_t)(b * SL + pos) * 1024 + col] = hnew;
  cs[(size_t)(b * SL + pos) * 1024 + col] = cnew;
}

// ---------------- precompute ALL segment argmax splits ----------------
__global__ __launch_bounds__(256)
void k_score(const float* __restrict__ E1, const float* __restrict__ Wr1,
             const float* __restrict__ Wr2, const int* __restrict__ len,
             int* __restrict__ ksplit)
{
  const int b = blockIdx.x;
  const int s = blockIdx.y;
  const int L = len[b];
  if (s + 2 > L) return;
  const int tid = threadIdx.x;
  __shared__ float e[32 * 257];
  __shared__ float w1p[256];
  __shared__ float w2s[256];
  __shared__ float red[32 * 8];
  __shared__ float sc[32];
  const int nrow = 32 - s;
  for (int i = tid; i < nrow * 256; i += 256) {
    const int rr = i >> 8, q = i & 255;
    e[rr * 257 + q] = E1[(size_t)(b * SL + s + rr) * 256 + q];
  }
  w1p[tid] = Wr1[tid * 513 + 512];
  w2s[tid] = Wr2[tid];
  __syncthreads();
  const int t_ = tid & 31, jg = tid >> 5;
  const int lmax = L - s;
  for (int l = 2; l <= lmax; ++l) {
    float part = 0.0f;
    if (t_ < l) {
      const float pos = 2.0f * (float)t_ / (float)l - 1.0f;
      const float* er = e + t_ * 257;
      for (int q = jg * 32; q < jg * 32 + 32; ++q) {
        const float v = er[q] + pos * w1p[q];
        part += fmaxf(v, 0.0f) * w2s[q];
      }
    }
    red[t_ * 8 + jg] = part;
    __syncthreads();
    if (jg == 0 && t_ < l) {
      float su = 0.0f;
      for (int q = 0; q < 8; ++q) su += red[t_ * 8 + q];
      sc[t_] = su;
    }
    __syncthreads();
    if (tid == 0) {
      int k = 0;
      float best = sc[0];
      for (int q = 1; q < l; ++q)
        if (sc[q] > best) { best = sc[q]; k = q; }
      ksplit[(b * 32 + s) * 33 + l] = k;
    }
    __syncthreads();
  }
}

// ---------------- DFS walk using precomputed splits ----------------
__global__ __launch_bounds__(64)
void k_walk(const int* __restrict__ ksplit, const int* __restrict__ len,
            int* __restrict__ meta)
{
  const int b = blockIdx.x;
  const int tid = threadIdx.x;
  __shared__ int ks[32 * 33];
  __shared__ int stk[96];
  for (int i = tid; i < 32 * 33; i += 64) ks[i] = ksplit[b * 1056 + i];
  __syncthreads();
  if (tid != 0) return;
  int* own = meta;
  int* lt = meta + 512;
  int* li = meta + 1024;
  int* rt = meta + 1536;
  int* ri = meta + 2048;
  int* dep = meta + 2560;
  int* nn = meta + 3072;
  int* dcnt = meta + 3088;
  int* lcnt = meta + 3120;
  int* dlist = meta + 3152;
  int* llist = meta + 19536;
  int sp = 0, nn_ = 1;
  stk[0] = 0; stk[1] = len[b]; stk[2] = 0;
  sp = 1;
  while (sp > 0) {
    sp--;
    const int s = stk[sp * 3], eN = stk[sp * 3 + 1], nid = stk[sp * 3 + 2];
    const int l = eN - s;
    const int k = ks[s * 33 + l];
    const int m = b * 32 + nid;
    own[m] = s + k;
    if (k == 0) { lt[m] = 0; li[m] = 0; }
    else if (k == 1) { lt[m] = 1; li[m] = s; }
    else {
      const int id = nn_++;
      lt[m] = 2; li[m] = id;
      stk[sp * 3] = s; stk[sp * 3 + 1] = s + k; stk[sp * 3 + 2] = id; sp++;
    }
    const int rl = l - k - 1;
    if (rl == 0) { rt[m] = 0; ri[m] = 0; }
    else if (rl == 1) { rt[m] = 1; ri[m] = s + k + 1; }
    else {
      const int id = nn_++;
      rt[m] = 2; ri[m] = id;
      stk[sp * 3] = s + k + 1; stk[sp * 3 + 1] = eN; stk[sp * 3 + 2] = id; sp++;
    }
  }
  nn[b] = nn_;
  for (int i = nn_ - 1; i >= 0; --i) {
    const int m = b * 32 + i;
    int d = 1;
    if (lt[m] == 2) d = max(d, dep[b * 32 + li[m]] + 1);
    if (rt[m] == 2) d = max(d, dep[b * 32 + ri[m]] + 1);
    dep[m] = d;
  }
  for (int i = 0; i < nn_; ++i) {
    const int m = b * 32 + i;
    const int r = dep[m];
    const int idx = atomicAdd(&dcnt[r], 1);
    dlist[r * 512 + idx] = m;
    if (lt[m] == 2 || rt[m] == 2) {
      const int lx = atomicAdd(&lcnt[r], 1);
      llist[r * 512 + lx] = m;
    }
  }
}

// ---------------- build U (bf16) = [hl_leaf|0 , hr_leaf|0 , hx] per node ----------------
__global__ __launch_bounds__(256)
void k_ubuild(const float* __restrict__ hs, const int* __restrict__ meta,
              unsigned short* __restrict__ U)
{
  const int id = blockIdx.x, b = blockIdx.y;
  const int tid = threadIdx.x;
  const int* own = meta;
  const int* lt = meta + 512;
  const int* li = meta + 1024;
  const int* rt = meta + 1536;
  const int* ri = meta + 2048;
  const int* nn = meta + 3072;
  const int m = b * 32 + id;
  unsigned short* u = U + (size_t)m * K3;
  if (id >= nn[b]) {
    for (int i = tid; i < K3; i += 256) u[i] = 0;
    return;
  }
  const float* hl = (lt[m] == 1) ? hs + (size_t)(b * 32 + li[m]) * 1024 : nullptr;
  const float* hr = (rt[m] == 1) ? hs + (size_t)(b * 32 + ri[m]) * 1024 : nullptr;
  const float* hx = hs + (size_t)(b * 32 + own[m]) * 1024;
  for (int i = tid; i < 1024; i += 256) {
    u[i] = hl ? f2bf(hl[i]) : 0;
    u[1024 + i] = hr ? f2bf(hr[i]) : 0;
    u[2048 + i] = f2bf(hx[i]);
  }
}

// ---------------- per-round link GEMM ----------------
// linkacc[node, g0:g0+16] = Wc[g0:g0+16, 0:2048] . [hl_int | hr_int]
// grid 320 (block b owns 16 Wc rows), block 256 = 4 waves (wave = k-quarter).
// B staged once to LDS (64 KB, k-major conflict-free); A fragments loaded
// straight from global (one uint4/lane/step, barrier-free pipelined k-loop).
__global__ __launch_bounds__(256)
void k_link(const unsigned short* __restrict__ WcB, const int* __restrict__ meta,
            const unsigned short* __restrict__ nodehb, float* __restrict__ linkacc,
            int r)
{
  const int* lt = meta + 512;
  const int* li = meta + 1024;
  const int* rt = meta + 1536;
  const int* ri = meta + 2048;
  const int* lcnt = meta + 3120;
  const int* llist = meta + 19536;
  const int cnt = lcnt[r];
  if (cnt == 0) return;
  __shared__ __align__(16) unsigned short Bs[16 * 2048];  // 64 KB exactly
  const int tid = threadIdx.x;
  const int g0 = blockIdx.x * 16;
  const int wave = tid >> 6, lane = tid & 63;
  const int l15 = lane & 15, quad = lane >> 4;
  const int kwin = wave * 512;           // this wave's k-window
  const int klbase = (kwin & 1023) + quad * 8;  // offset within the child vector
  const short8 z8 = {0, 0, 0, 0, 0, 0, 0, 0};

  for (int c0 = 0; c0 < cnt; c0 += MAXC * 16) {
    // ---- stage B (re-staged only if >128 nodes in round: rare) ----
    __syncthreads();
    {
      const int row = tid & 15;
      const int kqb = tid >> 4;
#pragma unroll
      for (int it = 0; it < 16; ++it) {
        const int kq = kqb + it * 16;
        *(uint4*)&Bs[kq * 128 + row * 8] =
            *(const uint4*)&WcB[(size_t)(g0 + row) * K3 + kq * 8];
      }
    }
    __syncthreads();
    const int nch = min((cnt - c0 + 15) >> 4, MAXC);
    floatx4 acc[MAXC];
    int myofs[MAXC];
    for (int c = 0; c < nch; ++c) {
      acc[c] = (floatx4){0.f, 0.f, 0.f, 0.f};
      int ofs = -1;
      const int m = c0 + c * 16 + l15;
      if (m < cnt) {
        const int node = llist[r * 512 + m];
        const int base = node & ~31;
        if (wave < 2) { if (lt[node] == 2) ofs = (base + li[node]) * 1024; }
        else          { if (rt[node] == 2) ofs = (base + ri[node]) * 1024; }
      }
      myofs[c] = ofs;
    }
    // ---- barrier-free MFMA k-loop ----
    for (int s = 0; s < 16; ++s) {
      const int k = kwin + s * 32 + quad * 8;
      const short8 b = *(const short8*)&Bs[(k >> 3) * 128 + l15 * 8];
      const int kl = klbase + s * 32;
      for (int c = 0; c < nch; ++c) {
        const short8 a = (myofs[c] >= 0)
            ? *(const short8*)&nodehb[(size_t)myofs[c] + kl] : z8;
        acc[c] = __builtin_amdgcn_mfma_f32_16x16x32_bf16(a, b, acc[c], 0, 0, 0);
      }
    }
    // ---- cross-wave reduce (reuse Bs as scratch) + store ----
    __syncthreads();
    float* scratch = (float*)Bs;   // nch*1024 floats <= 8192 (32 KB)
    for (int c = 0; c < nch; ++c) {
#pragma unroll
      for (int i = 0; i < 4; ++i)
        scratch[c * 1024 + wave * 256 + (quad * 4 + i) * 16 + l15] = acc[c][i];
    }
    __syncthreads();
    {
      const int mloc = tid >> 4, row = tid & 15;
      for (int c = 0; c < nch; ++c) {
        const int m = c0 + c * 16 + mloc;
        if (m < cnt) {
          const int node = llist[r * 512 + m];
          const float v = scratch[c * 1024 + 0 * 256 + mloc * 16 + row]
                        + scratch[c * 1024 + 1 * 256 + mloc * 16 + row]
                        + scratch[c * 1024 + 2 * 256 + mloc * 16 + row]
                        + scratch[c * 1024 + 3 * 256 + mloc * 16 + row];
          linkacc[(size_t)node * H5 + g0 + row] = v;
        }
      }
    }
  }
}

// ---------------- per-round gating (r=1: uselink=0) ----------------
__global__ __launch_bounds__(256)
void k_gate2(const float* __restrict__ gB, const float* __restrict__ cs,
             const float* __restrict__ linkacc, const int* __restrict__ meta,
             float* __restrict__ nodeh, float* __restrict__ nodec,
             unsigned short* __restrict__ nodehb, float* __restrict__ out,
             int r, int uselink)
{
  const int* lt = meta + 512;
  const int* li = meta + 1024;
  const int* rt = meta + 1536;
  const int* ri = meta + 2048;
  const int* dcnt = meta + 3088;
  const int* dlist = meta + 3152;
  const int cnt = dcnt[r];
  const int m = blockIdx.x;
  if (m >= cnt) return;
  const int node = dlist[r * 512 + m];
  const int base = node & ~31;
  const int ltv = lt[node], rtv = rt[node];
  const float* clp = (ltv == 2) ? &nodec[(size_t)(base + li[node]) * 1024]
                   : (ltv == 1) ? &cs[(size_t)(base + li[node]) * 1024] : nullptr;
  const float* crp = (rtv == 2) ? &nodec[(size_t)(base + ri[node]) * 1024]
                   : (rtv == 1) ? &cs[(size_t)(base + ri[node]) * 1024] : nullptr;
  const float* g = &gB[(size_t)node * H5];
  const float* la = &linkacc[(size_t)node * H5];
  const bool isroot = (node & 31) == 0;
  const int b = node >> 5;
  for (int q = 0; q < 4; ++q) {
    const int hj = q * 256 + threadIdx.x;
    float lk0 = 0.f, lk1 = 0.f, lk2 = 0.f, lk3 = 0.f, lk4 = 0.f;
    if (uselink) {
      lk0 = la[hj]; lk1 = la[1024 + hj]; lk2 = la[2048 + hj];
      lk3 = la[3072 + hj]; lk4 = la[4096 + hj];
    }
    const float gi  = g[hj] + lk0;
    const float gfl = g[1024 + hj] + lk1;
    const float gfr = g[2048 + hj] + lk2;
    const float gu  = g[3072 + hj] + lk3;
    const float go  = g[4096 + hj] + lk4;
    const float cl = clp ? clp[hj] : 0.0f;
    const float cr = crp ? crp[hj] : 0.0f;
    const float c = sigf(gfl) * cl + sigf(gfr) * cr + sigf(gi) * tanhf(gu);
    const float h = sigf(go) * tanhf(c);
    nodeh[(size_t)node * 1024 + hj] = h;
    nodec[(size_t)node * 1024 + hj] = c;
    nodehb[(size_t)node * 1024 + hj] = f2bf(h);
    if (isroot) {
      out[b * 1024 + hj] = h;
      out[16384 + b * 1024 + hj] = c;
    }
  }
}

extern "C" void kernel_launch(void* const* d_in, const int* in_sizes, int n_in,
                              void* d_out, int out_size, void* d_ws, size_t ws_size,
                              hipStream_t stream) {
  const float* emb = (const float*)d_in[0];
  const int* len = (const int*)d_in[1];
  const float* Wihf = (const float*)d_in[2];
  const float* Whhf = (const float*)d_in[3];
  const float* bf = (const float*)d_in[4];
  const float* Wihb = (const float*)d_in[5];
  const float* Whhb = (const float*)d_in[6];
  const float* bb = (const float*)d_in[7];
  const float* Wr1 = (const float*)d_in[8];
  const float* Wr2 = (const float*)d_in[9];
  const float* Wc = (const float*)d_in[10];
  const float* bc = (const float*)d_in[11];
  float* out = (float*)d_out;

  float* ws = (float*)d_ws;
  float* Xf = ws;                                         // 1048576 f
  float* Xb = Xf + 1048576;                               // 1048576 f
  float* hs = Xb + 1048576;                               // 524288 f
  float* cs = hs + 524288;                                // 524288 f
  float* E1 = cs + 524288;                                // 131072 f
  unsigned short* U = (unsigned short*)(E1 + 131072);     // 786432 f
  float* gB = (float*)U + 786432;                         // 2621440 f
  float* nodeh = gB + 2621440;                            // 524288 f
  float* nodec = nodeh + 524288;                          // 524288 f
  unsigned short* nodehb = (unsigned short*)(nodec + 524288);     // 262144 f
  float* cbuf = (float*)nodehb + 262144;                  // 32768 f
  unsigned short* hbB = (unsigned short*)(cbuf + 32768);  // 16384 f
  unsigned short* WcB = (unsigned short*)((float*)hbB + 16384);   // 7864320 f
  unsigned short* WihfB = WcB + 15728640;                 // 1048576 sh
  unsigned short* WihbB = WihfB + 1048576;
  unsigned short* WhhfB = WihbB + 1048576;
  unsigned short* WhhbB = WhhfB + 1048576;
  unsigned short* embB = WhhbB + 1048576;                 // 262144 sh
  int* meta = (int*)(embB + 262144);                      // ~36K ints
  int* ksplit = meta + 36096;                             // 16*1056 ints
  // linkacc (512 nodes x 5120 f = 10.5 MB) aliases Xf+Xb+hs, which are dead
  // by the time the rounds run (Xf/Xb after the scan, hs after k_ubuild).
  float* linkacc = ws;

  // zero c/h ping-pong state and per-depth counters
  k_zero<<<192, 256, 0, stream>>>(cbuf, 49152);
  k_zero<<<1, 64, 0, stream>>>((float*)(meta + 3088), 64);
  // bf16 conversions
  k_conv6<<<dim3(1920, 6), 256, 0, stream>>>(
      Wc, WcB, 15728640, Wihf, WihfB, 1048576, Wihb, WihbB, 1048576,
      Whhf, WhhfB, 1048576, Whhb, WhhbB, 1048576, emb, embB, 262144);
  // rank projection (f32)
  k_gemm<<<dim3(4, 8), 256, 0, stream>>>(emb, 512, Wr1, 513, E1, 256, 512);
  // input projections
  k_xproj<<<dim3(16, 4, 2), 256, 0, stream>>>(embB, WihfB, WihbB, Xf, Xb);
  // recurrent scan
  for (int t = 0; t < SL; ++t)
    k_stepm<<<dim3(32, 2), 256, 0, stream>>>(Xf, Xb, WhhfB, WhhbB, bf, bb, len,
                                             hbB, cbuf, hs, cs, t);
  // split table (parallel) + DFS walk (cheap)
  k_score<<<dim3(16, 31), 256, 0, stream>>>(E1, Wr1, Wr2, len, ksplit);
  k_walk<<<16, 64, 0, stream>>>(ksplit, len, meta);
  // precomputable part of every compose
  k_ubuild<<<dim3(32, 16), 256, 0, stream>>>(hs, meta, U);
  k_mfma_gemm<<<320, 256, 0, stream>>>(U, WcB, bc, gB);
  // round 1: gate-only (all children are leaves)
  k_gate2<<<512, 256, 0, stream>>>(gB, cs, linkacc, meta, nodeh, nodec, nodehb,
                                   out, 1, 0);
  // rounds >= 2: link GEMM + gating
  for (int r = 2; r <= 31; ++r) {
    k_link<<<320, 256, 0, stream>>>(WcB, meta, nodehb, linkacc, r);
    k_gate2<<<512, 256, 0, stream>>>(gB, cs, linkacc, meta, nodeh, nodec, nodehb,
                                     out, r, 1);
  }
}